// Round 14
// baseline (580.083 us; speedup 1.0000x reference)
//
#include <hip/hip_runtime.h>
#include <hip/hip_bf16.h>
#include <stdint.h>

typedef __attribute__((ext_vector_type(8))) short short8;
typedef __attribute__((ext_vector_type(4))) float floatx4;
typedef __attribute__((ext_vector_type(4))) unsigned int u32x4;
typedef unsigned short u16;
typedef unsigned int u32;
typedef unsigned long long u64;

static __device__ __forceinline__ u16 f2bf(float f) {
  union { float f; u32 u; } v; v.f = f;
  return (u16)((v.u + 0x7fffu + ((v.u >> 16) & 1u)) >> 16);
}
static __device__ __forceinline__ float bf2f(u16 h) {
  union { u32 u; float f; } v; v.u = ((u32)h) << 16; return v.f;
}
static __device__ __forceinline__ u64 pack4(float a, float b, float c, float d) {
  return (u64)f2bf(a) | ((u64)f2bf(b) << 16) | ((u64)f2bf(c) << 32) | ((u64)f2bf(d) << 48);
}

// ---------------- pre-GEMM conversions (vid/wih/bias; whh folded into gru, rest co-runs) ----------------
__global__ __launch_bounds__(256) void k_pre_cvt(
    const float* __restrict__ videos, const float* __restrict__ Wih_f,
    const float* __restrict__ Wih_b, const float* __restrict__ bih_f,
    const float* __restrict__ bih_b, const float* __restrict__ fcb,
    const float* __restrict__ gam, const float* __restrict__ bet,
    const float* __restrict__ mu, const float* __restrict__ var,
    u16* __restrict__ vid, u16* __restrict__ wih,
    float* __restrict__ bihcat, float* __restrict__ bns, float* __restrict__ bnt)
{
  const int O1 = 4194304;            // vid quads
  const int O2 = O1 + 786432;        // wih_f
  const int O3 = O2 + 786432;        // wih_b
  const int NQ = O3 + 1280;          // 768 bihcat quads + 512 bn quads
  for (int q = blockIdx.x * 256 + threadIdx.x; q < NQ; q += gridDim.x * 256) {
    if (q < O1) {
      float4 v = ((const float4*)videos)[q];
      ((u64*)vid)[q] = pack4(v.x, v.y, v.z, v.w);
    } else if (q < O2) {
      int r = q - O1; float4 v = ((const float4*)Wih_f)[r];
      ((u64*)wih)[r] = pack4(v.x, v.y, v.z, v.w);
    } else if (q < O3) {
      int r = q - O2; float4 v = ((const float4*)Wih_b)[r];
      ((u64*)wih)[r + 786432] = pack4(v.x, v.y, v.z, v.w);
    } else {
      int r = q - O3;
      if (r < 768) {
        int i = r * 4;  // 1536 % 4 == 0: quad never straddles f/b boundary
        const float* s = (i < 1536) ? (bih_f + i) : (bih_b + (i - 1536));
        *(float4*)&bihcat[i] = *(const float4*)s;
      } else {
        int i = (r - 768) * 4;
#pragma unroll
        for (int j = 0; j < 4; ++j) {
          int idx = i + j;
          float sc = gam[idx] * rsqrtf(var[idx] + 1e-5f);
          bns[idx] = sc;
          bnt[idx] = sc * (fcb[idx] - mu[idx]) + bet[idx];
        }
      }
    }
  }
}

static __device__ __forceinline__ void gload_lds16(const u16* g, u16* l) {
  __builtin_amdgcn_global_load_lds((const __attribute__((address_space(1))) u32*)(const void*)g,
                                   (__attribute__((address_space(3))) u32*)(void*)l, 16, 0, 0);
}

// ---------------- 256x256 8-phase bf16 GEMM (R8, proven) ----------------
static __device__ __forceinline__ void stage_half_256(
    const u16* __restrict__ Mat, long K, int rowbase, int ktile, u16* lregion,
    int tid, int wid)
{
  int srow = tid >> 3;
  int sce = (((tid >> 3) ^ tid) & 7) * 8;   // pre-swizzled source col (elems)
  const u16* g0 = Mat + (long)(rowbase + srow) * K + ktile * 64 + sce;
  const u16* g1 = Mat + (long)(rowbase + 64 + srow) * K + ktile * 64 + sce;
  gload_lds16(g0, lregion + wid * 512);
  gload_lds16(g1, lregion + 4096 + wid * 512);
}

#define GEMM256_BODY(A, Bm, K, NT)                                             \
  __shared__ u16 lds[65536];                                                   \
  int tid = threadIdx.x, lane = tid & 63, wid = tid >> 6;                      \
  int r16 = lane & 15, kq = lane >> 4;                                         \
  int wr = wid >> 2, wc = wid & 3;                                             \
  int nwg = gridDim.x * gridDim.y;                                             \
  int lin = blockIdx.y * gridDim.x + blockIdx.x;                               \
  int q8 = nwg >> 3;                                                           \
  int swz = (lin & 7) * q8 + (lin >> 3);                                       \
  int m0 = (swz / gridDim.x) * 256, n0 = (swz % gridDim.x) * 256;              \
  int fxor = (r16 & 7) << 4;                                                   \
  int c0 = (kq * 16) ^ fxor;                                                   \
  int c1 = c0 ^ 64;                                                            \
  int brow0 = (wc & 1) * 64;                                                   \
  const char* ldsc = (const char*)lds;                                         \
  const floatx4 z4 = {0.f, 0.f, 0.f, 0.f};                                     \
  floatx4 acc[8][4];                                                           \
  _Pragma("unroll")                                                            \
  for (int i = 0; i < 8; ++i)                                                  \
    _Pragma("unroll")                                                          \
    for (int j = 0; j < 4; ++j) acc[i][j] = z4;                                \
  stage_half_256(Bm, K, n0,       0, lds,                 tid, wid);           \
  stage_half_256(Bm, K, n0 + 128, 0, lds + 8192,          tid, wid);           \
  stage_half_256(A,  K, m0,       0, lds + 16384,         tid, wid);           \
  stage_half_256(A,  K, m0 + 128, 0, lds + 24576,         tid, wid);           \
  stage_half_256(Bm, K, n0,       1, lds + 32768,         tid, wid);           \
  stage_half_256(Bm, K, n0 + 128, 1, lds + 32768 + 8192,  tid, wid);           \
  stage_half_256(A,  K, m0,       1, lds + 32768 + 16384, tid, wid);           \
  stage_half_256(A,  K, m0 + 128, 1, lds + 32768 + 24576, tid, wid);           \
  asm volatile("s_waitcnt vmcnt(8)" ::: "memory");                             \
  asm volatile("s_barrier" ::: "memory");                                      \
  for (int T = 0; T < NT; ++T) {                                               \
    int P = T & 1;                                                             \
    int Tn1 = (T + 1 < NT) ? T + 1 : 0;                                        \
    int Tn2 = (T + 2 < NT) ? T + 2 : T + 2 - NT;                               \
    const char* bbase = ldsc + P * 65536 + (wc >> 1) * 16384;                  \
    const char* abase = ldsc + P * 65536 + 32768 + wr * 16384;                 \
    short8 bf[4][2];                                                           \
    {                                                                          \
      _Pragma("unroll")                                                        \
      for (int j = 0; j < 4; ++j) {                                            \
        bf[j][0] = *(const short8*)(bbase + (brow0 + j * 16 + r16) * 128 + c0);\
        bf[j][1] = *(const short8*)(bbase + (brow0 + j * 16 + r16) * 128 + c1);\
      }                                                                        \
      short8 af[2][2];                                                         \
      _Pragma("unroll")                                                        \
      for (int e = 0; e < 2; ++e) {                                            \
        af[e][0] = *(const short8*)(abase + (e * 16 + r16) * 128 + c0);        \
        af[e][1] = *(const short8*)(abase + (e * 16 + r16) * 128 + c1);        \
      }                                                                        \
      stage_half_256(A, K, m0, Tn1, lds + (Tn1 & 1) * 32768 + 16384, tid, wid);\
      asm volatile("s_barrier" ::: "memory");                                  \
      MFMA_CLUSTER(0)                                                          \
      asm volatile("s_barrier" ::: "memory");                                  \
    }                                                                          \
    {                                                                          \
      short8 af[2][2];                                                         \
      _Pragma("unroll")                                                        \
      for (int e = 0; e < 2; ++e) {                                            \
        af[e][0] = *(const short8*)(abase + ((2 + e) * 16 + r16) * 128 + c0);  \
        af[e][1] = *(const short8*)(abase + ((2 + e) * 16 + r16) * 128 + c1);  \
      }                                                                        \
      stage_half_256(A, K, m0 + 128, Tn1, lds + (Tn1 & 1) * 32768 + 24576, tid, wid); \
      asm volatile("s_barrier" ::: "memory");                                  \
      MFMA_CLUSTER(1)                                                          \
      asm volatile("s_barrier" ::: "memory");                                  \
    }                                                                          \
    {                                                                          \
      short8 af[2][2];                                                         \
      _Pragma("unroll")                                                        \
      for (int e = 0; e < 2; ++e) {                                            \
        af[e][0] = *(const short8*)(abase + ((4 + e) * 16 + r16) * 128 + c0);  \
        af[e][1] = *(const short8*)(abase + ((4 + e) * 16 + r16) * 128 + c1);  \
      }                                                                        \
      stage_half_256(Bm, K, n0, Tn2, lds + P * 32768, tid, wid);               \
      asm volatile("s_barrier" ::: "memory");                                  \
      MFMA_CLUSTER(2)                                                          \
      asm volatile("s_barrier" ::: "memory");                                  \
    }                                                                          \
    {                                                                          \
      short8 af[2][2];                                                         \
      _Pragma("unroll")                                                        \
      for (int e = 0; e < 2; ++e) {                                            \
        af[e][0] = *(const short8*)(abase + ((6 + e) * 16 + r16) * 128 + c0);  \
        af[e][1] = *(const short8*)(abase + ((6 + e) * 16 + r16) * 128 + c1);  \
      }                                                                        \
      stage_half_256(Bm, K, n0 + 128, Tn2, lds + P * 32768 + 8192, tid, wid);  \
      asm volatile("s_barrier" ::: "memory");                                  \
      MFMA_CLUSTER(3)                                                          \
      asm volatile("s_waitcnt vmcnt(4)" ::: "memory");                         \
      asm volatile("s_barrier" ::: "memory");                                  \
    }                                                                          \
  }

#define MFMA_CLUSTER(q)                                                        \
  asm volatile("s_waitcnt lgkmcnt(0)" ::: "memory");                           \
  __builtin_amdgcn_sched_barrier(0);                                           \
  __builtin_amdgcn_s_setprio(1);                                               \
  _Pragma("unroll")                                                            \
  for (int s = 0; s < 2; ++s)                                                  \
    _Pragma("unroll")                                                          \
    for (int e = 0; e < 2; ++e)                                                \
      _Pragma("unroll")                                                        \
      for (int j = 0; j < 4; ++j)                                              \
        acc[(q)*2 + e][j] = __builtin_amdgcn_mfma_f32_16x16x32_bf16(           \
            af[e][s], bf[j][s], acc[(q)*2 + e][j], 0, 0, 0);                   \
  __builtin_amdgcn_s_setprio(0);

// xg GEMM: f32 C out + shift (proven R8 epilogue)
__global__ __launch_bounds__(512) void gemm256(
    const u16* __restrict__ A, const u16* __restrict__ Bm,
    float* __restrict__ C, int N, int K, int NT,
    const float* __restrict__ shift)
{
  GEMM256_BODY(A, Bm, K, NT)
#pragma unroll
  for (int mf = 0; mf < 8; ++mf)
#pragma unroll
    for (int j = 0; j < 4; ++j) {
      int col = n0 + wc * 64 + j * 16 + r16;
      int row = m0 + wr * 128 + mf * 16 + kq * 4;
      float sh = shift ? shift[col] : 0.f;
#pragma unroll
      for (int qq = 0; qq < 4; ++qq)
        C[(long)(row + qq) * N + col] = acc[mf][j][qq] + sh;
    }
}

// conv GEMM with fused conv-finish (R12, proven)
__global__ __launch_bounds__(512) void gemm256c(
    const u16* __restrict__ A, const u16* __restrict__ Bm,
    u16* __restrict__ feat, const float* __restrict__ cb2,
    const float* __restrict__ cb3, const float* __restrict__ cb4,
    int K, int NT)
{
  GEMM256_BODY(A, Bm, K, NT)
  // drain staging DMAs before overwriting LDS with the z-tile
  asm volatile("s_waitcnt vmcnt(0)" ::: "memory");
  asm volatile("s_barrier" ::: "memory");
  u16* zt = lds;  // [256 rows][256 cols] bf16
#pragma unroll
  for (int mf = 0; mf < 8; ++mf)
#pragma unroll
    for (int j = 0; j < 4; ++j) {
      int col = wc * 64 + j * 16 + r16;
      int row = wr * 128 + mf * 16 + kq * 4;
#pragma unroll
      for (int qq = 0; qq < 4; ++qq)
        zt[(row + qq) * 256 + col] = f2bf(acc[mf][j][qq]);
    }
  __syncthreads();
  int S, k0, fo, ws;
  const float* cb;
  if (n0 < 1024)      { S = 2; k0 = n0 >> 1;          cb = cb2; fo = 1024; ws = 2; }
  else if (n0 < 3072) { S = 4; k0 = (n0 - 1024) >> 2; cb = cb3; fo = 1536; ws = 3; }
  else                { S = 4; k0 = (n0 - 3072) >> 2; cb = cb4; fo = 2048; ws = 4; }
  int KT = 256 / S;
  if (tid < 4 * KT) {
    int b = tid / KT, kk = tid % KT;
    float bias = cb[k0 + kk];
    float m = 0.f;  // relu floor
    for (int p = 0; p < 64 + ws - 1; ++p) {
      float a = bias;
      for (int j = 0; j < ws; ++j) {
        int t = p - (ws - 1) + j;
        if (t >= 0 && t < 64)
          a += bf2f(zt[(b * 64 + t) * 256 + kk * S + j]);
      }
      m = fmaxf(m, a);
    }
    int gb = (m0 >> 6) + b;
    feat[(long)gb * 5632 + fo + k0 + kk] = f2bf(m);
  }
}
#undef MFMA_CLUSTER
#undef GEMM256_BODY

// ---------------- GRU recurrence (R11 single-hop tagged exchange; proven) ----------------
// R13: whh conversion is now local — each recurrence block converts its own
// Whh f32 fragments at startup with the identical pack4 rounding (bit-same
// weights as the old pre-converted path); whh buffer + pre_cvt section gone.
__global__ __launch_bounds__(512) void gru_rec(
    const float* __restrict__ xg,     // [8192][3072]
    const float* __restrict__ Whh_f, const float* __restrict__ Whh_b,
    const float* __restrict__ bhh_f, const float* __restrict__ bhh_b,
    char* __restrict__ hb3,           // tagged exchange, 1MB, zeroed each launch
    u16* __restrict__ maskb,          // [8192][1024] bf16 masked output
    u16* __restrict__ feat,           // [128][5632] bf16 (gru mean + vo/mo sections)
    const int* __restrict__ lengths,  // [128]
    const float* __restrict__ fc_w, const float* __restrict__ w2,
    const float* __restrict__ w3, const float* __restrict__ w4,
    const float* __restrict__ vo, const float* __restrict__ mo,
    u16* __restrict__ fcw, u16* __restrict__ wc)
{
  __shared__ float part[2][4][3][256];
  __shared__ u16 hstage[8192];        // 16KB: h[16 batches][512 i] bf16, XOR-swizzled
  int tid = threadIdx.x, lane = tid & 63, wid = tid >> 6;
  int bid = blockIdx.x;

  if (bid >= 128) {
    // -------- converter blocks: fcw, wc remap (k-interleaved), vo/mo --------
    int cid = bid - 128;
    const int C1 = 2883584;           // fcw quads
    const int C2 = C1 + 1310720;      // wc quads (5120x1024/4)
    const int C3 = C2 + 65536;        // vo
    const int NQ = C3 + 32768;        // mo
    for (int q = cid * 512 + tid; q < NQ; q += 128 * 512) {
      if (q < C1) {
        float4 v = ((const float4*)fc_w)[q];
        ((u64*)fcw)[q] = pack4(v.x, v.y, v.z, v.w);
      } else if (q < C2) {
        int r = q - C1;
        int e = r << 2;
        int row = e >> 10, col = e & 1023;
        float4 v = {0.f, 0.f, 0.f, 0.f};
        if (row < 1024)      { int k = row >> 1, j = row & 1;
                               v = *(const float4*)(w2 + (k * 2 + j) * 1024 + col); }
        else if (row < 3072) { int m = row - 1024; int k = m >> 2, j = m & 3;
                               if (j < 3) v = *(const float4*)(w3 + (k * 3 + j) * 1024 + col); }
        else                 { int m = row - 3072; int k = m >> 2, j = m & 3;
                               v = *(const float4*)(w4 + (k * 4 + j) * 1024 + col); }
        ((u64*)wc)[r] = pack4(v.x, v.y, v.z, v.w);
      } else if (q < C3) {
        int r = q - C2; int b = r >> 9, c = (r & 511) * 4;
        float4 v = *(const float4*)&vo[(long)b * 2048 + c];
        *(u64*)&feat[(long)b * 5632 + 2560 + c] = pack4(v.x, v.y, v.z, v.w);
      } else {
        int r = q - C3; int b = r >> 8, c = (r & 255) * 4;
        float4 v = *(const float4*)&mo[(long)b * 1024 + c];
        *(u64*)&feat[(long)b * 5632 + 4608 + c] = pack4(v.x, v.y, v.z, v.w);
      }
    }
    return;
  }

  // -------- recurrence blocks --------
  int dir = bid >> 6, rem = bid & 63, bt = rem >> 3, is = rem & 7;
  int ih = wid & 3, ks = wid >> 2;
  int r16 = lane & 15, kq = lane >> 4;
  int iglob = is * 64 + ih * 16 + r16;
  int i0 = is * 64 + ih * 16 + kq * 4;
  int batch = bt * 16 + r16;
  const float* bhh = dir ? bhh_b : bhh_f;
  const floatx4 z4 = {0.f, 0.f, 0.f, 0.f};
  int len = lengths[batch];

  // local whh conversion (bit-identical pack4 rounding vs old pre-cvt path)
  const float* whsrc = dir ? Whh_b : Whh_f;
  short8 wfrag[3][8];
#pragma unroll
  for (int g = 0; g < 3; ++g) {
    const float* wrow = whsrc + (long)(g * 512 + iglob) * 512;
#pragma unroll
    for (int kk = 0; kk < 8; ++kk) {
      const float* p = wrow + (ks * 8 + kk) * 32 + kq * 8;
      float4 a = *(const float4*)p;
      float4 b = *(const float4*)(p + 4);
      union { u64 q[2]; short8 v; } u;
      u.q[0] = pack4(a.x, a.y, a.z, a.w);
      u.q[1] = pack4(b.x, b.y, b.z, b.w);
      wfrag[g][kk] = u.v;
    }
  }
  float4 bh4[3];
#pragma unroll
  for (int g = 0; g < 3; ++g) bh4[g] = *(const float4*)&bhh[g * 512 + i0];
  float4 hprev = {0.f, 0.f, 0.f, 0.f};
  float4 msum = {0.f, 0.f, 0.f, 0.f};

  float4 px[3];
  if (ks == 0) {
    int ts0 = dir ? 63 : 0;
    long xb = (long)(batch * 64 + ts0) * 3072 + dir * 1536 + i0;
#pragma unroll
    for (int g = 0; g < 3; ++g) px[g] = *(const float4*)&xg[xb + g * 512];
  }

  char* slot[2];
  slot[0] = hb3 + (long)((0 * 2 + dir) * 8 + bt) * 32768;
  slot[1] = hb3 + (long)((1 * 2 + dir) * 8 + bt) * 32768;
  char* sdst[4];
#pragma unroll
  for (int k = 0; k < 4; ++k) {
    int row = 4 * k + (tid >> 7);
    int colb = (tid & 127) * 8;
    sdst[k] = (char*)hstage + row * 1024 + (colb ^ ((row & 7) << 4));
  }
  int ld_off = tid * 16;
  int p0 = r16 * 256 + is * 32 + ih * 8 + kq * 2;
  int rb = r16 * 1024 + ks * 512 + kq * 16;
  int rsw = (r16 & 7) << 4;

  for (int t = 0; t < 64; ++t) {
    int par = t & 1;
    u32 tg = (u32)t;
    const char* sb = slot[par];
    u32x4 L0, L1, L2, L3;
    while (true) {
      asm volatile(
        "global_load_dwordx4 %0, %4, off sc0 sc1\n\t"
        "global_load_dwordx4 %1, %5, off sc0 sc1\n\t"
        "global_load_dwordx4 %2, %6, off sc0 sc1\n\t"
        "global_load_dwordx4 %3, %7, off sc0 sc1\n\t"
        "s_waitcnt vmcnt(0)"
        : "=&v"(L0), "=&v"(L1), "=&v"(L2), "=&v"(L3)
        : "v"(sb + ld_off), "v"(sb + 8192 + ld_off),
          "v"(sb + 16384 + ld_off), "v"(sb + 24576 + ld_off)
        : "memory");
      bool ok = (L0.y == tg) & (L0.w == tg) & (L1.y == tg) & (L1.w == tg) &
                (L2.y == tg) & (L2.w == tg) & (L3.y == tg) & (L3.w == tg);
      if (ok) break;
      __builtin_amdgcn_s_sleep(1);
    }
    *(u64*)sdst[0] = (u64)L0.x | ((u64)L0.z << 32);
    *(u64*)sdst[1] = (u64)L1.x | ((u64)L1.z << 32);
    *(u64*)sdst[2] = (u64)L2.x | ((u64)L2.z << 32);
    *(u64*)sdst[3] = (u64)L3.x | ((u64)L3.z << 32);
    float4 pxn[3];
    if (ks == 0 && t < 63) {
      int ts1 = dir ? (62 - t) : (t + 1);
      long xb = (long)(batch * 64 + ts1) * 3072 + dir * 1536 + i0;
#pragma unroll
      for (int g = 0; g < 3; ++g) pxn[g] = *(const float4*)&xg[xb + g * 512];
    }
    asm volatile("s_waitcnt lgkmcnt(0)\n\ts_barrier" ::: "memory");
    floatx4 acc[3];
#pragma unroll
    for (int g = 0; g < 3; ++g) acc[g] = z4;
#pragma unroll
    for (int kk = 0; kk < 8; ++kk) {
      short8 hv = *(const short8*)((const char*)hstage + ((rb + kk * 64) ^ rsw));
#pragma unroll
      for (int g = 0; g < 3; ++g)
        acc[g] = __builtin_amdgcn_mfma_f32_16x16x32_bf16(wfrag[g][kk], hv, acc[g], 0, 0, 0);
    }
    if (ks == 1) {
#pragma unroll
      for (int g = 0; g < 3; ++g) *(floatx4*)&part[par][ih][g][lane * 4] = acc[g];
    }
    asm volatile("s_waitcnt lgkmcnt(0)\n\ts_barrier" ::: "memory");
    if (ks == 0) {
      int tsrc = dir ? (63 - t) : t;
#pragma unroll
      for (int g = 0; g < 3; ++g) acc[g] += *(const floatx4*)&part[par][ih][g][lane * 4];
      float4 hn4;
#pragma unroll
      for (int q = 0; q < 4; ++q) {
        float rr = acc[0][q] + ((const float*)&bh4[0])[q] + ((const float*)&px[0])[q];
        float zz = acc[1][q] + ((const float*)&bh4[1])[q] + ((const float*)&px[1])[q];
        float r = 1.f / (1.f + __expf(-rr));
        float z = 1.f / (1.f + __expf(-zz));
        float n = tanhf(((const float*)&px[2])[q] + r * (acc[2][q] + ((const float*)&bh4[2])[q]));
        ((float*)&hn4)[q] = (1.f - z) * n + z * ((const float*)&hprev)[q];
      }
      hprev = hn4;
      u64 hval = pack4(hn4.x, hn4.y, hn4.z, hn4.w);
      if (t < 63) {
        u32 tg1 = (u32)(t + 1);
        char* pb = slot[(t + 1) & 1] + p0 * 8;
        u64 v0 = (u64)(u32)hval | ((u64)tg1 << 32);
        u64 v1 = (u64)(u32)(hval >> 32) | ((u64)tg1 << 32);
        asm volatile("global_atomic_swap_x2 %0, %1, off sc1"
                     :: "v"(pb), "v"(v0) : "memory");
        asm volatile("global_atomic_swap_x2 %0, %1, off sc1"
                     :: "v"(pb + 8), "v"(v1) : "memory");
      }
      bool mv = tsrc < len;
      *(u64*)&maskb[(long)(batch * 64 + tsrc) * 1024 + dir * 512 + i0] = mv ? hval : 0ull;
      if (mv) {
        msum.x += hn4.x; msum.y += hn4.y; msum.z += hn4.z; msum.w += hn4.w;
      }
      px[0] = pxn[0]; px[1] = pxn[1]; px[2] = pxn[2];
    }
  }
  if (ks == 0) {
    float inv = 1.0f / (float)len;
    *(u64*)&feat[(long)batch * 5632 + dir * 512 + i0] =
        pack4(msum.x * inv, msum.y * inv, msum.z * inv, msum.w * inv);
  }
}

// ---------------- fused FC GEMM (split-K x8) + BN + row L2 normalize ----------------
// Cooperative: 128 blocks (16 col-tiles x 8 K-splits). Phase 1 = 128^2 GEMM
// partial (sc0 sc1 stores -> LLC-visible), per-wave vmcnt(0) drain, one
// global_atomic_add sc1 per block; spin until 128 (release/acquire identical
// in shape to the proven gru flag protocol). Phase 2 = each block l2norms one
// batch row, reading partials sc0 sc1.
__global__ __launch_bounds__(256) void k_fc_l2(
    const u16* __restrict__ A, const u16* __restrict__ Bm,
    float* __restrict__ fcp, const float* __restrict__ bns,
    const float* __restrict__ bnt, float* __restrict__ out,
    int* __restrict__ ctr)
{
  __shared__ u16 As[128 * 32];
  __shared__ u16 Bs[128 * 32];
  __shared__ float red[4];
  int tid = threadIdx.x, lane = tid & 63, wid = tid >> 6;
  const int N = 2048, K = 5632, kn = 22;
  int n0 = (blockIdx.x & 15) * 128;
  int kt0 = (blockIdx.x >> 4) * kn;
  int wr = wid >> 1, wcl = wid & 1;
  int r16 = lane & 15, kq = lane >> 4;
  const floatx4 z4 = {0.f, 0.f, 0.f, 0.f};
  floatx4 acc[4][4];
#pragma unroll
  for (int i = 0; i < 4; ++i)
#pragma unroll
    for (int j = 0; j < 4; ++j) acc[i][j] = z4;
  for (int kt = kt0; kt < kt0 + kn; ++kt) {
    __syncthreads();
#pragma unroll
    for (int inst = 0; inst < 2; ++inst) {
      int g = inst * 256 + tid;
      int row = g >> 2, cb = g & 3;
      const u16* ga = A + (long)row * K + kt * 32 + cb * 8;
      const u16* gb = Bm + (long)(n0 + row) * K + kt * 32 + cb * 8;
      gload_lds16(ga, &As[(inst * 256 + wid * 64) * 8]);
      gload_lds16(gb, &Bs[(inst * 256 + wid * 64) * 8]);
    }
    __syncthreads();
    short8 af[4], bf[4];
#pragma unroll
    for (int mt = 0; mt < 4; ++mt) af[mt] = *(const short8*)&As[(wr * 64 + mt * 16 + r16) * 32 + kq * 8];
#pragma unroll
    for (int nt = 0; nt < 4; ++nt) bf[nt] = *(const short8*)&Bs[(wcl * 64 + nt * 16 + r16) * 32 + kq * 8];
#pragma unroll
    for (int mt = 0; mt < 4; ++mt)
#pragma unroll
      for (int nt = 0; nt < 4; ++nt)
        acc[mt][nt] = __builtin_amdgcn_mfma_f32_16x16x32_bf16(af[mt], bf[nt], acc[mt][nt], 0, 0, 0);
  }
  float* Cp = fcp + (long)(blockIdx.x >> 4) * 128 * 2048;
#pragma unroll
  for (int nt = 0; nt < 4; ++nt) {
    int col = n0 + wcl * 64 + nt * 16 + r16;
#pragma unroll
    for (int mt = 0; mt < 4; ++mt)
#pragma unroll
      for (int q = 0; q < 4; ++q) {
        int row = wr * 64 + mt * 16 + kq * 4 + q;
        float v = acc[mt][nt][q];
        asm volatile("global_store_dword %0, %1, off sc0 sc1"
                     :: "v"(&Cp[(long)row * 2048 + col]), "v"(v) : "memory");
      }
  }
  asm volatile("s_waitcnt vmcnt(0)" ::: "memory");
  __syncthreads();
  if (tid == 0) {
    int one = 1;
    asm volatile("global_atomic_add %0, %1, off sc1" :: "v"(ctr), "v"(one) : "memory");
    while (true) {
      int v;
      asm volatile("global_load_dword %0, %1, off sc0 sc1\n\ts_waitcnt vmcnt(0)"
                   : "=v"(v) : "v"(ctr) : "memory");
      if (v >= 128) break;
      __builtin_amdgcn_s_sleep(1);
    }
  }
  __syncthreads();
  // phase 2: l2norm for batch b = blockIdx.x
  int b = blockIdx.x;
  float vv[8]; float s = 0.f;
#pragma unroll
  for (int j = 0; j < 8; ++j) {
    int i = j * 256 + tid;
    long o = (long)b * 2048 + i;
    float a = 0.f;
#pragma unroll
    for (int zz = 0; zz < 8; ++zz) {
      float pv;
      asm volatile("global_load_dword %0, %1, off sc0 sc1\n\ts_waitcnt vmcnt(0)"
                   : "=v"(pv) : "v"(&fcp[o + (long)zz * 262144]) : "memory");
      a += pv;
    }
    a = a * bns[i] + bnt[i];
    vv[j] = a; s += a * a;
  }
#pragma unroll
  for (int o = 32; o > 0; o >>= 1) s += __shfl_down(s, o);
  if ((tid & 63) == 0) red[tid >> 6] = s;
  __syncthreads();
  float rn = rsqrtf(red[0] + red[1] + red[2] + red[3]);
#pragma unroll
  for (int j = 0; j < 8; ++j)
    out[(long)b * 2048 + j * 256 + tid] = vv[j] * rn;
}

// ---------------- launch ----------------
extern "C" void kernel_launch(void* const* d_in, const int* in_sizes, int n_in,
                              void* d_out, int out_size, void* d_ws, size_t ws_size,
                              hipStream_t stream)
{
  (void)in_sizes; (void)n_in; (void)out_size; (void)ws_size;
  const float* videos       = (const float*)d_in[0];
  const float* motions      = (const float*)d_in[1];
  const float* videos_origin= (const float*)d_in[2];
  const int*   lengths      = (const int*)d_in[3];
  const float* Wih_f = (const float*)d_in[4];
  const float* Whh_f = (const float*)d_in[5];
  const float* bih_f = (const float*)d_in[6];
  const float* bhh_f = (const float*)d_in[7];
  const float* Wih_b = (const float*)d_in[8];
  const float* Whh_b = (const float*)d_in[9];
  const float* bih_b = (const float*)d_in[10];
  const float* bhh_b = (const float*)d_in[11];
  const float* fc_w  = (const float*)d_in[12];
  const float* fc_b  = (const float*)d_in[13];
  const float* bn_gamma = (const float*)d_in[14];
  const float* bn_beta  = (const float*)d_in[15];
  const float* bn_mean  = (const float*)d_in[16];
  const float* bn_var   = (const float*)d_in[17];
  const float* conv_w2 = (const float*)d_in[18];
  const float* conv_b2 = (const float*)d_in[19];
  const float* conv_w3 = (const float*)d_in[20];
  const float* conv_b3 = (const float*)d_in[21];
  const float* conv_w4 = (const float*)d_in[22];
  const float* conv_b4 = (const float*)d_in[23];
  float* out = (float*)d_out;
  char* w = (char*)d_ws;

  const size_t XG    = 0;              // 8192x3072 f32 = 100,663,296
  const size_t HS    = 100663296;      // dead region: tagged exchange (1MB) + ctr + Wc
  const size_t VID   = 134217728;      // 8192x2048 bf16 = 33,554,432
  const size_t MASKB = 167772160;      // 8192x1024 bf16 = 16,777,216 (FC partials 8MB overlay)
  const size_t WIH   = 184549376;      // 3072x2048 bf16 = 12,582,912
  const size_t FCW   = 209715200;      // 2048x5632 bf16 = 23,068,672
  const size_t FEAT  = 232783872;      // 128x5632 bf16 = 1,441,792
  const size_t BIH   = 235274240;      // 3072 f32
  const size_t BNS   = 235286528;      // 2048 f32
  const size_t BNT   = 235294720;      // 2048 f32

  float* xg   = (float*)(w + XG);
  char* hb3   = (char*)(w + HS);               // tagged exchange (1MB)
  int* ctr    = (int*)(w + HS + 1048576);      // FC grid-sync counter (zeroed)
  u16* wc_    = (u16*)(w + HS + 1052672);      // Wc [5120][1024] bf16 (10.5MB)
  u16* vid    = (u16*)(w + VID);
  u16* maskb  = (u16*)(w + MASKB);
  float* fcp  = (float*)(w + MASKB);   // FC split-K partials overlay (after conv GEMM)
  u16* wih    = (u16*)(w + WIH);
  u16* fcw    = (u16*)(w + FCW);
  u16* feat   = (u16*)(w + FEAT);
  float* bih  = (float*)(w + BIH);
  float* bns  = (float*)(w + BNS);
  float* bnt  = (float*)(w + BNT);

  // zero tagged exchange (tags 0 expected at t=0; data 0 = h0) + FC counter
  hipMemsetAsync(hb3, 0, 1048576 + 4096, stream);

  k_pre_cvt<<<4096, 256, 0, stream>>>(
      videos, Wih_f, Wih_b, bih_f, bih_b,
      fc_b, bn_gamma, bn_beta, bn_mean, bn_var,
      vid, wih, bih, bns, bnt);

  // xg = videos @ [Wih_f;Wih_b]^T + bih  (f32 out), 256^2 8-phase
  gemm256<<<dim3(12, 32), 512, 0, stream>>>(vid, wih, xg, 3072, 2048, 32, bih);

  {
    const float* xg_c = xg;
    const float* whf_c = Whh_f; const float* whb_c = Whh_b;
    char* hb_c = hb3; u16* mb_c = maskb; u16* ft_c = feat;
    const int* len_c = lengths;
    const float* bf_c = bhh_f; const float* bb_c = bhh_b;
    const float* fw_c = fc_w; const float* w2_c = conv_w2;
    const float* w3_c = conv_w3; const float* w4_c = conv_w4;
    const float* vo_c = videos_origin; const float* mo_c = motions;
    u16* fcw_c = fcw; u16* wc_c = wc_;
    void* args[] = { (void*)&xg_c, (void*)&whf_c, (void*)&whb_c,
                     (void*)&bf_c, (void*)&bb_c,
                     (void*)&hb_c, (void*)&mb_c, (void*)&ft_c, (void*)&len_c,
                     (void*)&fw_c, (void*)&w2_c, (void*)&w3_c, (void*)&w4_c,
                     (void*)&vo_c, (void*)&mo_c, (void*)&fcw_c, (void*)&wc_c };
    hipLaunchCooperativeKernel(reinterpret_cast<void*>(gru_rec), dim3(256), dim3(512), args, 0, stream);
  }

  // conv GEMM with fused conv-finish (k-interleaved Wc, N=5120), writes feat directly
  gemm256c<<<dim3(20, 32), 512, 0, stream>>>(maskb, wc_, feat, conv_b2, conv_b3, conv_b4, 1024, 16);

  // fused FC split-K x8 + BN + l2norm (cooperative, counter grid-sync)
  {
    const u16* ft_c = feat; const u16* fcw_c = fcw;
    float* fcp_c = fcp; const float* bns_c = bns; const float* bnt_c = bnt;
    float* out_c = out; int* ctr_c = ctr;
    void* args[] = { (void*)&ft_c, (void*)&fcw_c, (void*)&fcp_c,
                     (void*)&bns_c, (void*)&bnt_c, (void*)&out_c, (void*)&ctr_c };
    hipLaunchCooperativeKernel(reinterpret_cast<void*>(k_fc_l2), dim3(128), dim3(256), args, 0, stream);
  }
}

// Round 15
// 519.657 us; speedup vs baseline: 1.1163x; 1.1163x over previous
//
#include <hip/hip_runtime.h>
#include <hip/hip_bf16.h>
#include <stdint.h>

typedef __attribute__((ext_vector_type(8))) short short8;
typedef __attribute__((ext_vector_type(4))) float floatx4;
typedef __attribute__((ext_vector_type(4))) unsigned int u32x4;
typedef unsigned short u16;
typedef unsigned int u32;
typedef unsigned long long u64;

static __device__ __forceinline__ u16 f2bf(float f) {
  union { float f; u32 u; } v; v.f = f;
  return (u16)((v.u + 0x7fffu + ((v.u >> 16) & 1u)) >> 16);
}
static __device__ __forceinline__ float bf2f(u16 h) {
  union { u32 u; float f; } v; v.u = ((u32)h) << 16; return v.f;
}
static __device__ __forceinline__ u64 pack4(float a, float b, float c, float d) {
  return (u64)f2bf(a) | ((u64)f2bf(b) << 16) | ((u64)f2bf(c) << 32) | ((u64)f2bf(d) << 48);
}

// ---------------- pre-GEMM conversions (vid/wih/whh/bias only; rest co-runs with gru) ----------------
__global__ __launch_bounds__(256) void k_pre_cvt(
    const float* __restrict__ videos, const float* __restrict__ Wih_f,
    const float* __restrict__ Wih_b, const float* __restrict__ Whh_f,
    const float* __restrict__ Whh_b, const float* __restrict__ bih_f,
    const float* __restrict__ bih_b, const float* __restrict__ fcb,
    const float* __restrict__ gam, const float* __restrict__ bet,
    const float* __restrict__ mu, const float* __restrict__ var,
    u16* __restrict__ vid, u16* __restrict__ wih, u16* __restrict__ whh,
    float* __restrict__ bihcat, float* __restrict__ bns, float* __restrict__ bnt)
{
  const int O1 = 4194304;            // vid quads
  const int O2 = O1 + 786432;        // wih_f
  const int O3 = O2 + 786432;        // wih_b
  const int O4 = O3 + 196608;        // whh_f
  const int O5 = O4 + 196608;        // whh_b
  const int NQ = O5 + 1280;          // 768 bihcat quads + 512 bn quads
  for (int q = blockIdx.x * 256 + threadIdx.x; q < NQ; q += gridDim.x * 256) {
    if (q < O1) {
      float4 v = ((const float4*)videos)[q];
      ((u64*)vid)[q] = pack4(v.x, v.y, v.z, v.w);
    } else if (q < O2) {
      int r = q - O1; float4 v = ((const float4*)Wih_f)[r];
      ((u64*)wih)[r] = pack4(v.x, v.y, v.z, v.w);
    } else if (q < O3) {
      int r = q - O2; float4 v = ((const float4*)Wih_b)[r];
      ((u64*)wih)[r + 786432] = pack4(v.x, v.y, v.z, v.w);
    } else if (q < O4) {
      int r = q - O3; float4 v = ((const float4*)Whh_f)[r];
      ((u64*)whh)[r] = pack4(v.x, v.y, v.z, v.w);
    } else if (q < O5) {
      int r = q - O4; float4 v = ((const float4*)Whh_b)[r];
      ((u64*)whh)[r + 196608] = pack4(v.x, v.y, v.z, v.w);
    } else {
      int r = q - O5;
      if (r < 768) {
        int i = r * 4;  // 1536 % 4 == 0: quad never straddles f/b boundary
        const float* s = (i < 1536) ? (bih_f + i) : (bih_b + (i - 1536));
        *(float4*)&bihcat[i] = *(const float4*)s;
      } else {
        int i = (r - 768) * 4;
#pragma unroll
        for (int j = 0; j < 4; ++j) {
          int idx = i + j;
          float sc = gam[idx] * rsqrtf(var[idx] + 1e-5f);
          bns[idx] = sc;
          bnt[idx] = sc * (fcb[idx] - mu[idx]) + bet[idx];
        }
      }
    }
  }
}

static __device__ __forceinline__ void gload_lds16(const u16* g, u16* l) {
  __builtin_amdgcn_global_load_lds((const __attribute__((address_space(1))) u32*)(const void*)g,
                                   (__attribute__((address_space(3))) u32*)(void*)l, 16, 0, 0);
}

// ---------------- 256x256 8-phase bf16 GEMM (R8, proven) ----------------
static __device__ __forceinline__ void stage_half_256(
    const u16* __restrict__ Mat, long K, int rowbase, int ktile, u16* lregion,
    int tid, int wid)
{
  int srow = tid >> 3;
  int sce = (((tid >> 3) ^ tid) & 7) * 8;   // pre-swizzled source col (elems)
  const u16* g0 = Mat + (long)(rowbase + srow) * K + ktile * 64 + sce;
  const u16* g1 = Mat + (long)(rowbase + 64 + srow) * K + ktile * 64 + sce;
  gload_lds16(g0, lregion + wid * 512);
  gload_lds16(g1, lregion + 4096 + wid * 512);
}

#define GEMM256_BODY(A, Bm, K, NT)                                             \
  __shared__ u16 lds[65536];                                                   \
  int tid = threadIdx.x, lane = tid & 63, wid = tid >> 6;                      \
  int r16 = lane & 15, kq = lane >> 4;                                         \
  int wr = wid >> 2, wc = wid & 3;                                             \
  int nwg = gridDim.x * gridDim.y;                                             \
  int lin = blockIdx.y * gridDim.x + blockIdx.x;                               \
  int q8 = nwg >> 3;                                                           \
  int swz = (lin & 7) * q8 + (lin >> 3);                                       \
  int m0 = (swz / gridDim.x) * 256, n0 = (swz % gridDim.x) * 256;              \
  int fxor = (r16 & 7) << 4;                                                   \
  int c0 = (kq * 16) ^ fxor;                                                   \
  int c1 = c0 ^ 64;                                                            \
  int brow0 = (wc & 1) * 64;                                                   \
  const char* ldsc = (const char*)lds;                                         \
  const floatx4 z4 = {0.f, 0.f, 0.f, 0.f};                                     \
  floatx4 acc[8][4];                                                           \
  _Pragma("unroll")                                                            \
  for (int i = 0; i < 8; ++i)                                                  \
    _Pragma("unroll")                                                          \
    for (int j = 0; j < 4; ++j) acc[i][j] = z4;                                \
  stage_half_256(Bm, K, n0,       0, lds,                 tid, wid);           \
  stage_half_256(Bm, K, n0 + 128, 0, lds + 8192,          tid, wid);           \
  stage_half_256(A,  K, m0,       0, lds + 16384,         tid, wid);           \
  stage_half_256(A,  K, m0 + 128, 0, lds + 24576,         tid, wid);           \
  stage_half_256(Bm, K, n0,       1, lds + 32768,         tid, wid);           \
  stage_half_256(Bm, K, n0 + 128, 1, lds + 32768 + 8192,  tid, wid);           \
  stage_half_256(A,  K, m0,       1, lds + 32768 + 16384, tid, wid);           \
  stage_half_256(A,  K, m0 + 128, 1, lds + 32768 + 24576, tid, wid);           \
  asm volatile("s_waitcnt vmcnt(8)" ::: "memory");                             \
  asm volatile("s_barrier" ::: "memory");                                      \
  for (int T = 0; T < NT; ++T) {                                               \
    int P = T & 1;                                                             \
    int Tn1 = (T + 1 < NT) ? T + 1 : 0;                                        \
    int Tn2 = (T + 2 < NT) ? T + 2 : T + 2 - NT;                               \
    const char* bbase = ldsc + P * 65536 + (wc >> 1) * 16384;                  \
    const char* abase = ldsc + P * 65536 + 32768 + wr * 16384;                 \
    short8 bf[4][2];                                                           \
    {                                                                          \
      _Pragma("unroll")                                                        \
      for (int j = 0; j < 4; ++j) {                                            \
        bf[j][0] = *(const short8*)(bbase + (brow0 + j * 16 + r16) * 128 + c0);\
        bf[j][1] = *(const short8*)(bbase + (brow0 + j * 16 + r16) * 128 + c1);\
      }                                                                        \
      short8 af[2][2];                                                         \
      _Pragma("unroll")                                                        \
      for (int e = 0; e < 2; ++e) {                                            \
        af[e][0] = *(const short8*)(abase + (e * 16 + r16) * 128 + c0);        \
        af[e][1] = *(const short8*)(abase + (e * 16 + r16) * 128 + c1);        \
      }                                                                        \
      stage_half_256(A, K, m0, Tn1, lds + (Tn1 & 1) * 32768 + 16384, tid, wid);\
      asm volatile("s_barrier" ::: "memory");                                  \
      MFMA_CLUSTER(0)                                                          \
      asm volatile("s_barrier" ::: "memory");                                  \
    }                                                                          \
    {                                                                          \
      short8 af[2][2];                                                         \
      _Pragma("unroll")                                                        \
      for (int e = 0; e < 2; ++e) {                                            \
        af[e][0] = *(const short8*)(abase + ((2 + e) * 16 + r16) * 128 + c0);  \
        af[e][1] = *(const short8*)(abase + ((2 + e) * 16 + r16) * 128 + c1);  \
      }                                                                        \
      stage_half_256(A, K, m0 + 128, Tn1, lds + (Tn1 & 1) * 32768 + 24576, tid, wid); \
      asm volatile("s_barrier" ::: "memory");                                  \
      MFMA_CLUSTER(1)                                                          \
      asm volatile("s_barrier" ::: "memory");                                  \
    }                                                                          \
    {                                                                          \
      short8 af[2][2];                                                         \
      _Pragma("unroll")                                                        \
      for (int e = 0; e < 2; ++e) {                                            \
        af[e][0] = *(const short8*)(abase + ((4 + e) * 16 + r16) * 128 + c0);  \
        af[e][1] = *(const short8*)(abase + ((4 + e) * 16 + r16) * 128 + c1);  \
      }                                                                        \
      stage_half_256(Bm, K, n0, Tn2, lds + P * 32768, tid, wid);               \
      asm volatile("s_barrier" ::: "memory");                                  \
      MFMA_CLUSTER(2)                                                          \
      asm volatile("s_barrier" ::: "memory");                                  \
    }                                                                          \
    {                                                                          \
      short8 af[2][2];                                                         \
      _Pragma("unroll")                                                        \
      for (int e = 0; e < 2; ++e) {                                            \
        af[e][0] = *(const short8*)(abase + ((6 + e) * 16 + r16) * 128 + c0);  \
        af[e][1] = *(const short8*)(abase + ((6 + e) * 16 + r16) * 128 + c1);  \
      }                                                                        \
      stage_half_256(Bm, K, n0 + 128, Tn2, lds + P * 32768 + 8192, tid, wid);  \
      asm volatile("s_barrier" ::: "memory");                                  \
      MFMA_CLUSTER(3)                                                          \
      asm volatile("s_waitcnt vmcnt(4)" ::: "memory");                         \
      asm volatile("s_barrier" ::: "memory");                                  \
    }                                                                          \
  }

#define MFMA_CLUSTER(q)                                                        \
  asm volatile("s_waitcnt lgkmcnt(0)" ::: "memory");                           \
  __builtin_amdgcn_sched_barrier(0);                                           \
  __builtin_amdgcn_s_setprio(1);                                               \
  _Pragma("unroll")                                                            \
  for (int s = 0; s < 2; ++s)                                                  \
    _Pragma("unroll")                                                          \
    for (int e = 0; e < 2; ++e)                                                \
      _Pragma("unroll")                                                        \
      for (int j = 0; j < 4; ++j)                                              \
        acc[(q)*2 + e][j] = __builtin_amdgcn_mfma_f32_16x16x32_bf16(           \
            af[e][s], bf[j][s], acc[(q)*2 + e][j], 0, 0, 0);                   \
  __builtin_amdgcn_s_setprio(0);

// xg GEMM: f32 C out + shift (proven R8 epilogue)
__global__ __launch_bounds__(512) void gemm256(
    const u16* __restrict__ A, const u16* __restrict__ Bm,
    float* __restrict__ C, int N, int K, int NT,
    const float* __restrict__ shift)
{
  GEMM256_BODY(A, Bm, K, NT)
#pragma unroll
  for (int mf = 0; mf < 8; ++mf)
#pragma unroll
    for (int j = 0; j < 4; ++j) {
      int col = n0 + wc * 64 + j * 16 + r16;
      int row = m0 + wr * 128 + mf * 16 + kq * 4;
      float sh = shift ? shift[col] : 0.f;
#pragma unroll
      for (int qq = 0; qq < 4; ++qq)
        C[(long)(row + qq) * N + col] = acc[mf][j][qq] + sh;
    }
}

// conv GEMM with fused conv-finish (R12, proven).
// Wc layout is k-interleaved: section ws2 rows [0,1024) = k*2+j; ws3 rows
// [1024,3072) = 1024 + k*4 + j (j=3 zero-padded); ws4 rows [3072,5120) =
// 3072 + k*4 + j. Tiles never straddle sections; each 256-col N-tile holds
// ALL j columns for its k-range and each 256-row M-tile holds ALL 64
// timesteps of its 4 batches -> shift-add + relu + max closes in-block.
__global__ __launch_bounds__(512) void gemm256c(
    const u16* __restrict__ A, const u16* __restrict__ Bm,
    u16* __restrict__ feat, const float* __restrict__ cb2,
    const float* __restrict__ cb3, const float* __restrict__ cb4,
    int K, int NT)
{
  GEMM256_BODY(A, Bm, K, NT)
  // drain staging DMAs before overwriting LDS with the z-tile
  asm volatile("s_waitcnt vmcnt(0)" ::: "memory");
  asm volatile("s_barrier" ::: "memory");
  u16* zt = lds;  // [256 rows][256 cols] bf16
#pragma unroll
  for (int mf = 0; mf < 8; ++mf)
#pragma unroll
    for (int j = 0; j < 4; ++j) {
      int col = wc * 64 + j * 16 + r16;
      int row = wr * 128 + mf * 16 + kq * 4;
#pragma unroll
      for (int qq = 0; qq < 4; ++qq)
        zt[(row + qq) * 256 + col] = f2bf(acc[mf][j][qq]);
    }
  __syncthreads();
  int S, k0, fo, ws;
  const float* cb;
  if (n0 < 1024)      { S = 2; k0 = n0 >> 1;          cb = cb2; fo = 1024; ws = 2; }
  else if (n0 < 3072) { S = 4; k0 = (n0 - 1024) >> 2; cb = cb3; fo = 1536; ws = 3; }
  else                { S = 4; k0 = (n0 - 3072) >> 2; cb = cb4; fo = 2048; ws = 4; }
  int KT = 256 / S;
  if (tid < 4 * KT) {
    int b = tid / KT, kk = tid % KT;
    float bias = cb[k0 + kk];
    float m = 0.f;  // relu floor
    for (int p = 0; p < 64 + ws - 1; ++p) {
      float a = bias;
      for (int j = 0; j < ws; ++j) {
        int t = p - (ws - 1) + j;
        if (t >= 0 && t < 64)
          a += bf2f(zt[(b * 64 + t) * 256 + kk * S + j]);
      }
      m = fmaxf(m, a);
    }
    int gb = (m0 >> 6) + b;
    feat[(long)gb * 5632 + fo + k0 + kk] = f2bf(m);
  }
}
#undef MFMA_CLUSTER
#undef GEMM256_BODY

// ---------------- 128x128 MFMA GEMM (kept for the small FC GEMM) ----------------
__global__ __launch_bounds__(256) void gemm_bt(
    const u16* __restrict__ A, const u16* __restrict__ Bm,
    float* __restrict__ C, int M, int N, int K, int kn)
{
  __shared__ u16 As[128 * 32];
  __shared__ u16 Bs[128 * 32];
  int tid = threadIdx.x, lane = tid & 63, wid = tid >> 6;
  int nwg = gridDim.x * gridDim.y;
  int lin = blockIdx.y * gridDim.x + blockIdx.x;
  int q8 = nwg >> 3;
  int swz = (lin & 7) * q8 + (lin >> 3);
  int m0 = (swz / gridDim.x) * 128, n0 = (swz % gridDim.x) * 128;
  int kt0 = blockIdx.z * kn;
  int wr = wid >> 1, wc = wid & 1;
  int r16 = lane & 15, kq = lane >> 4;
  const floatx4 z4 = {0.f, 0.f, 0.f, 0.f};
  floatx4 acc[4][4];
#pragma unroll
  for (int i = 0; i < 4; ++i)
#pragma unroll
    for (int j = 0; j < 4; ++j) acc[i][j] = z4;
  for (int kt = kt0; kt < kt0 + kn; ++kt) {
    __syncthreads();
#pragma unroll
    for (int inst = 0; inst < 2; ++inst) {
      int g = inst * 256 + tid;
      int row = g >> 2, cb = g & 3;
      const u16* ga = A + (long)(m0 + row) * K + kt * 32 + cb * 8;
      const u16* gb = Bm + (long)(n0 + row) * K + kt * 32 + cb * 8;
      gload_lds16(ga, &As[(inst * 256 + wid * 64) * 8]);
      gload_lds16(gb, &Bs[(inst * 256 + wid * 64) * 8]);
    }
    __syncthreads();
    short8 af[4], bf[4];
#pragma unroll
    for (int mt = 0; mt < 4; ++mt) af[mt] = *(const short8*)&As[(wr * 64 + mt * 16 + r16) * 32 + kq * 8];
#pragma unroll
    for (int nt = 0; nt < 4; ++nt) bf[nt] = *(const short8*)&Bs[(wc * 64 + nt * 16 + r16) * 32 + kq * 8];
#pragma unroll
    for (int mt = 0; mt < 4; ++mt)
#pragma unroll
      for (int nt = 0; nt < 4; ++nt)
        acc[mt][nt] = __builtin_amdgcn_mfma_f32_16x16x32_bf16(af[mt], bf[nt], acc[mt][nt], 0, 0, 0);
  }
  float* Cp = C + (long)blockIdx.z * M * N;
#pragma unroll
  for (int nt = 0; nt < 4; ++nt) {
    int col = n0 + wc * 64 + nt * 16 + r16;
#pragma unroll
    for (int mt = 0; mt < 4; ++mt)
#pragma unroll
      for (int q = 0; q < 4; ++q) {
        int row = m0 + wr * 64 + mt * 16 + kq * 4 + q;
        Cp[(long)row * N + col] = acc[mt][nt][q];
      }
  }
}

// ---------------- GRU recurrence (R11 single-hop tagged exchange; proven) ----------------
__global__ __launch_bounds__(512) void gru_rec(
    const float* __restrict__ xg,     // [8192][3072]
    const u16* __restrict__ whhb,     // [2][1536][512] bf16
    const float* __restrict__ bhh_f, const float* __restrict__ bhh_b,
    char* __restrict__ hb3,           // tagged exchange, 1MB, zeroed each launch
    u16* __restrict__ maskb,          // [8192][1024] bf16 masked output
    u16* __restrict__ feat,           // [128][5632] bf16 (gru mean + vo/mo sections)
    const int* __restrict__ lengths,  // [128]
    const float* __restrict__ fc_w, const float* __restrict__ w2,
    const float* __restrict__ w3, const float* __restrict__ w4,
    const float* __restrict__ vo, const float* __restrict__ mo,
    u16* __restrict__ fcw, u16* __restrict__ wc)
{
  __shared__ float part[2][4][3][256];
  __shared__ u16 hstage[8192];        // 16KB: h[16 batches][512 i] bf16, XOR-swizzled
  int tid = threadIdx.x, lane = tid & 63, wid = tid >> 6;
  int bid = blockIdx.x;

  if (bid >= 128) {
    // -------- converter blocks: fcw, wc remap (k-interleaved), vo/mo --------
    int cid = bid - 128;
    const int C1 = 2883584;           // fcw quads
    const int C2 = C1 + 1310720;      // wc quads (5120x1024/4)
    const int C3 = C2 + 65536;        // vo
    const int NQ = C3 + 32768;        // mo
    for (int q = cid * 512 + tid; q < NQ; q += 128 * 512) {
      if (q < C1) {
        float4 v = ((const float4*)fc_w)[q];
        ((u64*)fcw)[q] = pack4(v.x, v.y, v.z, v.w);
      } else if (q < C2) {
        int r = q - C1;
        int e = r << 2;
        int row = e >> 10, col = e & 1023;
        float4 v = {0.f, 0.f, 0.f, 0.f};
        if (row < 1024)      { int k = row >> 1, j = row & 1;
                               v = *(const float4*)(w2 + (k * 2 + j) * 1024 + col); }
        else if (row < 3072) { int m = row - 1024; int k = m >> 2, j = m & 3;
                               if (j < 3) v = *(const float4*)(w3 + (k * 3 + j) * 1024 + col); }
        else                 { int m = row - 3072; int k = m >> 2, j = m & 3;
                               v = *(const float4*)(w4 + (k * 4 + j) * 1024 + col); }
        ((u64*)wc)[r] = pack4(v.x, v.y, v.z, v.w);
      } else if (q < C3) {
        int r = q - C2; int b = r >> 9, c = (r & 511) * 4;
        float4 v = *(const float4*)&vo[(long)b * 2048 + c];
        *(u64*)&feat[(long)b * 5632 + 2560 + c] = pack4(v.x, v.y, v.z, v.w);
      } else {
        int r = q - C3; int b = r >> 8, c = (r & 255) * 4;
        float4 v = *(const float4*)&mo[(long)b * 1024 + c];
        *(u64*)&feat[(long)b * 5632 + 4608 + c] = pack4(v.x, v.y, v.z, v.w);
      }
    }
    return;
  }

  // -------- recurrence blocks --------
  int dir = bid >> 6, rem = bid & 63, bt = rem >> 3, is = rem & 7;
  int ih = wid & 3, ks = wid >> 2;
  int r16 = lane & 15, kq = lane >> 4;
  int iglob = is * 64 + ih * 16 + r16;
  int i0 = is * 64 + ih * 16 + kq * 4;
  int batch = bt * 16 + r16;
  const float* bhh = dir ? bhh_b : bhh_f;
  const floatx4 z4 = {0.f, 0.f, 0.f, 0.f};
  int len = lengths[batch];

  short8 wfrag[3][8];
#pragma unroll
  for (int g = 0; g < 3; ++g) {
    const u16* wrow = whhb + (long)(dir * 1536 + g * 512 + iglob) * 512;
#pragma unroll
    for (int kk = 0; kk < 8; ++kk)
      wfrag[g][kk] = *(const short8*)&wrow[(ks * 8 + kk) * 32 + kq * 8];
  }
  float4 bh4[3];
#pragma unroll
  for (int g = 0; g < 3; ++g) bh4[g] = *(const float4*)&bhh[g * 512 + i0];
  float4 hprev = {0.f, 0.f, 0.f, 0.f};
  float4 msum = {0.f, 0.f, 0.f, 0.f};

  float4 px[3];
  if (ks == 0) {
    int ts0 = dir ? 63 : 0;
    long xb = (long)(batch * 64 + ts0) * 3072 + dir * 1536 + i0;
#pragma unroll
    for (int g = 0; g < 3; ++g) px[g] = *(const float4*)&xg[xb + g * 512];
  }

  char* slot[2];
  slot[0] = hb3 + (long)((0 * 2 + dir) * 8 + bt) * 32768;
  slot[1] = hb3 + (long)((1 * 2 + dir) * 8 + bt) * 32768;
  char* sdst[4];
#pragma unroll
  for (int k = 0; k < 4; ++k) {
    int row = 4 * k + (tid >> 7);
    int colb = (tid & 127) * 8;
    sdst[k] = (char*)hstage + row * 1024 + (colb ^ ((row & 7) << 4));
  }
  int ld_off = tid * 16;
  int p0 = r16 * 256 + is * 32 + ih * 8 + kq * 2;
  int rb = r16 * 1024 + ks * 512 + kq * 16;
  int rsw = (r16 & 7) << 4;

  for (int t = 0; t < 64; ++t) {
    int par = t & 1;
    u32 tg = (u32)t;
    const char* sb = slot[par];
    u32x4 L0, L1, L2, L3;
    while (true) {
      asm volatile(
        "global_load_dwordx4 %0, %4, off sc0 sc1\n\t"
        "global_load_dwordx4 %1, %5, off sc0 sc1\n\t"
        "global_load_dwordx4 %2, %6, off sc0 sc1\n\t"
        "global_load_dwordx4 %3, %7, off sc0 sc1\n\t"
        "s_waitcnt vmcnt(0)"
        : "=&v"(L0), "=&v"(L1), "=&v"(L2), "=&v"(L3)
        : "v"(sb + ld_off), "v"(sb + 8192 + ld_off),
          "v"(sb + 16384 + ld_off), "v"(sb + 24576 + ld_off)
        : "memory");
      bool ok = (L0.y == tg) & (L0.w == tg) & (L1.y == tg) & (L1.w == tg) &
                (L2.y == tg) & (L2.w == tg) & (L3.y == tg) & (L3.w == tg);
      if (ok) break;
      __builtin_amdgcn_s_sleep(1);
    }
    *(u64*)sdst[0] = (u64)L0.x | ((u64)L0.z << 32);
    *(u64*)sdst[1] = (u64)L1.x | ((u64)L1.z << 32);
    *(u64*)sdst[2] = (u64)L2.x | ((u64)L2.z << 32);
    *(u64*)sdst[3] = (u64)L3.x | ((u64)L3.z << 32);
    float4 pxn[3];
    if (ks == 0 && t < 63) {
      int ts1 = dir ? (62 - t) : (t + 1);
      long xb = (long)(batch * 64 + ts1) * 3072 + dir * 1536 + i0;
#pragma unroll
      for (int g = 0; g < 3; ++g) pxn[g] = *(const float4*)&xg[xb + g * 512];
    }
    asm volatile("s_waitcnt lgkmcnt(0)\n\ts_barrier" ::: "memory");
    floatx4 acc[3];
#pragma unroll
    for (int g = 0; g < 3; ++g) acc[g] = z4;
#pragma unroll
    for (int kk = 0; kk < 8; ++kk) {
      short8 hv = *(const short8*)((const char*)hstage + ((rb + kk * 64) ^ rsw));
#pragma unroll
      for (int g = 0; g < 3; ++g)
        acc[g] = __builtin_amdgcn_mfma_f32_16x16x32_bf16(wfrag[g][kk], hv, acc[g], 0, 0, 0);
    }
    if (ks == 1) {
#pragma unroll
      for (int g = 0; g < 3; ++g) *(floatx4*)&part[par][ih][g][lane * 4] = acc[g];
    }
    asm volatile("s_waitcnt lgkmcnt(0)\n\ts_barrier" ::: "memory");
    if (ks == 0) {
      int tsrc = dir ? (63 - t) : t;
#pragma unroll
      for (int g = 0; g < 3; ++g) acc[g] += *(const floatx4*)&part[par][ih][g][lane * 4];
      float4 hn4;
#pragma unroll
      for (int q = 0; q < 4; ++q) {
        float rr = acc[0][q] + ((const float*)&bh4[0])[q] + ((const float*)&px[0])[q];
        float zz = acc[1][q] + ((const float*)&bh4[1])[q] + ((const float*)&px[1])[q];
        float r = 1.f / (1.f + __expf(-rr));
        float z = 1.f / (1.f + __expf(-zz));
        float n = tanhf(((const float*)&px[2])[q] + r * (acc[2][q] + ((const float*)&bh4[2])[q]));
        ((float*)&hn4)[q] = (1.f - z) * n + z * ((const float*)&hprev)[q];
      }
      hprev = hn4;
      u64 hval = pack4(hn4.x, hn4.y, hn4.z, hn4.w);
      if (t < 63) {
        u32 tg1 = (u32)(t + 1);
        char* pb = slot[(t + 1) & 1] + p0 * 8;
        u64 v0 = (u64)(u32)hval | ((u64)tg1 << 32);
        u64 v1 = (u64)(u32)(hval >> 32) | ((u64)tg1 << 32);
        asm volatile("global_atomic_swap_x2 %0, %1, off sc1"
                     :: "v"(pb), "v"(v0) : "memory");
        asm volatile("global_atomic_swap_x2 %0, %1, off sc1"
                     :: "v"(pb + 8), "v"(v1) : "memory");
      }
      bool mv = tsrc < len;
      *(u64*)&maskb[(long)(batch * 64 + tsrc) * 1024 + dir * 512 + i0] = mv ? hval : 0ull;
      if (mv) {
        msum.x += hn4.x; msum.y += hn4.y; msum.z += hn4.z; msum.w += hn4.w;
      }
      px[0] = pxn[0]; px[1] = pxn[1]; px[2] = pxn[2];
    }
  }
  if (ks == 0) {
    float inv = 1.0f / (float)len;
    *(u64*)&feat[(long)batch * 5632 + dir * 512 + i0] =
        pack4(msum.x * inv, msum.y * inv, msum.z * inv, msum.w * inv);
  }
}

// ---------------- split-K reduce + BN + row L2 normalize (8 partials) ----------------
__global__ __launch_bounds__(256) void k_l2norm(const float* __restrict__ p,
    const float* __restrict__ bns, const float* __restrict__ bnt, float* __restrict__ out)
{
  __shared__ float red[4];
  int b = blockIdx.x, tid = threadIdx.x;
  float v[8]; float s = 0.f;
#pragma unroll
  for (int j = 0; j < 8; ++j) {
    int i = j * 256 + tid;
    long o = (long)b * 2048 + i;
    float a = 0.f;
#pragma unroll
    for (int zz = 0; zz < 8; ++zz) a += p[o + (long)zz * 262144];
    a = a * bns[i] + bnt[i];
    v[j] = a; s += a * a;
  }
#pragma unroll
  for (int o = 32; o > 0; o >>= 1) s += __shfl_down(s, o);
  if ((tid & 63) == 0) red[tid >> 6] = s;
  __syncthreads();
  float rn = rsqrtf(red[0] + red[1] + red[2] + red[3]);
#pragma unroll
  for (int j = 0; j < 8; ++j)
    out[(long)b * 2048 + j * 256 + tid] = v[j] * rn;
}

// ---------------- launch ----------------
extern "C" void kernel_launch(void* const* d_in, const int* in_sizes, int n_in,
                              void* d_out, int out_size, void* d_ws, size_t ws_size,
                              hipStream_t stream)
{
  (void)in_sizes; (void)n_in; (void)out_size; (void)ws_size;
  const float* videos       = (const float*)d_in[0];
  const float* motions      = (const float*)d_in[1];
  const float* videos_origin= (const float*)d_in[2];
  const int*   lengths      = (const int*)d_in[3];
  const float* Wih_f = (const float*)d_in[4];
  const float* Whh_f = (const float*)d_in[5];
  const float* bih_f = (const float*)d_in[6];
  const float* bhh_f = (const float*)d_in[7];
  const float* Wih_b = (const float*)d_in[8];
  const float* Whh_b = (const float*)d_in[9];
  const float* bih_b = (const float*)d_in[10];
  const float* bhh_b = (const float*)d_in[11];
  const float* fc_w  = (const float*)d_in[12];
  const float* fc_b  = (const float*)d_in[13];
  const float* bn_gamma = (const float*)d_in[14];
  const float* bn_beta  = (const float*)d_in[15];
  const float* bn_mean  = (const float*)d_in[16];
  const float* bn_var   = (const float*)d_in[17];
  const float* conv_w2 = (const float*)d_in[18];
  const float* conv_b2 = (const float*)d_in[19];
  const float* conv_w3 = (const float*)d_in[20];
  const float* conv_b3 = (const float*)d_in[21];
  const float* conv_w4 = (const float*)d_in[22];
  const float* conv_b4 = (const float*)d_in[23];
  float* out = (float*)d_out;
  char* w = (char*)d_ws;

  const size_t XG    = 0;              // 8192x3072 f32 = 100,663,296
  const size_t HS    = 100663296;      // dead region: tagged h exchange (1MB) + Wc (10.5MB)
  const size_t VID   = 134217728;      // 8192x2048 bf16 = 33,554,432
  const size_t MASKB = 167772160;      // 8192x1024 bf16 = 16,777,216 (FC partials 8MB overlay)
  const size_t WIH   = 184549376;      // 3072x2048 bf16 = 12,582,912
  const size_t WHH   = 197132288;      // 2x1536x512 bf16 = 3,145,728
  const size_t FCW   = 209715200;      // 2048x5632 bf16 = 23,068,672
  const size_t FEAT  = 232783872;      // 128x5632 bf16 = 1,441,792
  const size_t BIH   = 235274240;      // 3072 f32
  const size_t BNS   = 235286528;      // 2048 f32
  const size_t BNT   = 235294720;      // 2048 f32

  float* xg   = (float*)(w + XG);
  char* hb3   = (char*)(w + HS);               // tagged exchange (1MB)
  u16* wc_    = (u16*)(w + HS + 1048576);      // Wc [5120][1024] bf16 (10.5MB, HS region)
  u16* vid    = (u16*)(w + VID);
  u16* maskb  = (u16*)(w + MASKB);
  float* fcp  = (float*)(w + MASKB);   // FC split-K partials overlay (after conv GEMM)
  u16* wih    = (u16*)(w + WIH);
  u16* whh    = (u16*)(w + WHH);
  u16* fcw    = (u16*)(w + FCW);
  u16* feat   = (u16*)(w + FEAT);
  float* bih  = (float*)(w + BIH);
  float* bns  = (float*)(w + BNS);
  float* bnt  = (float*)(w + BNT);

  // zero tagged exchange (tags 0 expected at t=0; data 0 = h0), every launch
  hipMemsetAsync(hb3, 0, 1048576, stream);

  k_pre_cvt<<<4096, 256, 0, stream>>>(
      videos, Wih_f, Wih_b, Whh_f, Whh_b, bih_f, bih_b,
      fc_b, bn_gamma, bn_beta, bn_mean, bn_var,
      vid, wih, whh, bih, bns, bnt);

  // xg = videos @ [Wih_f;Wih_b]^T + bih  (f32 out), 256^2 8-phase
  gemm256<<<dim3(12, 32), 512, 0, stream>>>(vid, wih, xg, 3072, 2048, 32, bih);

  {
    const float* xg_c = xg; const u16* whh_c = whh;
    char* hb_c = hb3; u16* mb_c = maskb; u16* ft_c = feat;
    const int* len_c = lengths;
    const float* bf_c = bhh_f; const float* bb_c = bhh_b;
    const float* fw_c = fc_w; const float* w2_c = conv_w2;
    const float* w3_c = conv_w3; const float* w4_c = conv_w4;
    const float* vo_c = videos_origin; const float* mo_c = motions;
    u16* fcw_c = fcw; u16* wc_c = wc_;
    void* args[] = { (void*)&xg_c, (void*)&whh_c, (void*)&bf_c, (void*)&bb_c,
                     (void*)&hb_c, (void*)&mb_c, (void*)&ft_c, (void*)&len_c,
                     (void*)&fw_c, (void*)&w2_c, (void*)&w3_c, (void*)&w4_c,
                     (void*)&vo_c, (void*)&mo_c, (void*)&fcw_c, (void*)&wc_c };
    hipLaunchCooperativeKernel(reinterpret_cast<void*>(gru_rec), dim3(256), dim3(512), args, 0, stream);
  }

  // conv GEMM with fused conv-finish (k-interleaved Wc, N=5120), writes feat directly
  gemm256c<<<dim3(20, 32), 512, 0, stream>>>(maskb, wc_, feat, conv_b2, conv_b3, conv_b4, 1024, 16);
  // FC split-K x8 (raw partials; BN folded into l2norm)
  gemm_bt<<<dim3(16, 1, 8), 256, 0, stream>>>(feat, fcw, fcp, 128, 2048, 5632, 22);
  k_l2norm<<<128, 256, 0, stream>>>(fcp, bns, bnt, out);
}